// Round 2
// baseline (332.137 us; speedup 1.0000x reference)
//
#include <hip/hip_runtime.h>
#include <stdint.h>

#define N_NODES 2048
#define F_DIM   1024
#define HEADS   4
#define NF      4096
#define E_EDGES 16384
#define MAXE    (E_EDGES + N_NODES)
#define BN_EPS  1e-5f
#define NSLOPE  0.2f

// canonical small-tensor offsets (elements, all multiples of 8 for 16B alignment)
#define CW1   0
#define CB1   256
#define CG1   272
#define CBE1  288
#define CBL   304
#define CBR   4400
#define CATT  8496
#define CBG   12592
#define CW2   16688
#define CB2   17712
#define CG2   17728
#define CBE2  17744
#define CSM_N 17760

typedef unsigned short ushort_t;
typedef __attribute__((ext_vector_type(8))) short bf16x8;
typedef __attribute__((ext_vector_type(4))) float f32x4;
typedef __attribute__((ext_vector_type(8))) unsigned short us8;

__device__ __forceinline__ float b2f(unsigned short u) {
    union { unsigned int i; float f; } x; x.i = ((unsigned int)u) << 16; return x.f;
}
__device__ __forceinline__ unsigned short f2b(float f) {
    union { float f; unsigned int i; } x; x.f = f;
    unsigned int r = x.i + 0x7fffu + ((x.i >> 16) & 1u);
    return (unsigned short)(r >> 16);
}

// ------------------------------------------------------------- dtype sniff
// flags[0]=1 if float tensors are fp32 (else bf16); flags[1]=1 if edge_index int64
__global__ void k_sniff(const ushort_t* __restrict__ xu, const int* __restrict__ ei,
                        int* __restrict__ flags)
{
    if (threadIdx.x == 0) {
        int hits = 0;
        for (int i = 0; i < 32; ++i) {
            unsigned e = (xu[2 * i] >> 7) & 0xFF;
            if (e >= 0x90) hits++;          // |v| >= 2^17: impossible for bf16 N(0,1)
        }
        flags[0] = (hits >= 3) ? 1 : 0;
        int nz = 0;
        for (int i = 0; i < 32; ++i) if (ei[2 * i + 1] != 0) nz++;
        flags[1] = (nz == 0) ? 1 : 0;       // int64 high words are all zero
    }
}

// ------------------------------------------------------------- zero ints
__global__ void k_zero(int* __restrict__ p) { p[blockIdx.x * 256 + threadIdx.x] = 0; }

// ------------------------------------------------------------- canonicalize inputs
__device__ __forceinline__ ushort_t ld_canon(const void* src, size_t i, int f32) {
    return f32 ? f2b(((const float*)src)[i]) : ((const ushort_t*)src)[i];
}

__global__ __launch_bounds__(256) void k_convert_all(
    const int* __restrict__ flags,
    const void* x, const void* ei,
    const void* w1, const void* b1, const void* g1, const void* be1,
    const void* bl, const void* br, const void* att, const void* bg,
    const void* w2, const void* b2, const void* g2, const void* be2,
    ushort_t* __restrict__ cx, int* __restrict__ cei, ushort_t* __restrict__ csm)
{
    int f32 = flags[0], i64 = flags[1];
    int b = blockIdx.x, t = threadIdx.x;
    if (b < 2048) {                       // x: 2M elements
        size_t base = (size_t)b * 1024;
        #pragma unroll
        for (int i = 0; i < 4; ++i) {
            size_t idx = base + t + i * 256;
            cx[idx] = ld_canon(x, idx, f32);
        }
    } else if (b == 2048) {               // all small tensors
        for (int i = t; i < 256; i += 256)  csm[CW1 + i]  = ld_canon(w1, i, f32);
        for (int i = t; i < 16; i += 256)   csm[CB1 + i]  = ld_canon(b1, i, f32);
        for (int i = t; i < 16; i += 256)   csm[CG1 + i]  = ld_canon(g1, i, f32);
        for (int i = t; i < 16; i += 256)   csm[CBE1 + i] = ld_canon(be1, i, f32);
        for (int i = t; i < 4096; i += 256) csm[CBL + i]  = ld_canon(bl, i, f32);
        for (int i = t; i < 4096; i += 256) csm[CBR + i]  = ld_canon(br, i, f32);
        for (int i = t; i < 4096; i += 256) csm[CATT + i] = ld_canon(att, i, f32);
        for (int i = t; i < 4096; i += 256) csm[CBG + i]  = ld_canon(bg, i, f32);
        for (int i = t; i < 1024; i += 256) csm[CW2 + i]  = ld_canon(w2, i, f32);
        for (int i = t; i < 16; i += 256)   csm[CB2 + i]  = ld_canon(b2, i, f32);
        for (int i = t; i < 16; i += 256)   csm[CG2 + i]  = ld_canon(g2, i, f32);
        for (int i = t; i < 16; i += 256)   csm[CBE2 + i] = ld_canon(be2, i, f32);
    } else {                              // edge_index: 32768 ints, 32 blocks
        const int* s = (const int*)ei;
        int base = (b - 2049) * 1024;
        #pragma unroll
        for (int j = 0; j < 4; ++j) {
            int idx = base + t + j * 256;
            cei[idx] = i64 ? s[2 * idx] : s[idx];
        }
    }
}

// ------------------------------------------------- fc1 (conv1x1 16->16) + BN1 partials
__global__ __launch_bounds__(256) void k_fc1_stats(
    const ushort_t* __restrict__ cx, const ushort_t* __restrict__ csm,
    float* __restrict__ y0, float* __restrict__ ps, float* __restrict__ pq)
{
    __shared__ float xs[1024];
    __shared__ float sw[256];
    __shared__ float sb[16];
    int tid = threadIdx.x;
    sw[tid] = b2f(csm[CW1 + tid]);
    if (tid < 16) sb[tid] = b2f(csm[CB1 + tid]);
    int wave = tid >> 6, lane = tid & 63;
    float s[4] = {0,0,0,0}, q[4] = {0,0,0,0};
    for (int nn = 0; nn < 8; ++nn) {
        int n = blockIdx.x * 8 + nn;
        __syncthreads();
        #pragma unroll
        for (int i = 0; i < 4; ++i) {
            int idx = tid + i * 256;
            xs[idx] = b2f(cx[(size_t)n * 1024 + idx]);
        }
        __syncthreads();
        #pragma unroll
        for (int i = 0; i < 4; ++i) {
            int o = wave * 4 + i;
            float acc = sb[o];
            #pragma unroll
            for (int c = 0; c < 16; ++c) acc += xs[c * 64 + lane] * sw[o * 16 + c];
            y0[(size_t)n * 1024 + o * 64 + lane] = acc;
            s[i] += acc; q[i] += acc * acc;
        }
    }
    #pragma unroll
    for (int i = 0; i < 4; ++i)
        for (int mm = 1; mm < 64; mm <<= 1) {
            s[i] += __shfl_xor(s[i], mm);
            q[i] += __shfl_xor(q[i], mm);
        }
    if (lane == 0)
        #pragma unroll
        for (int i = 0; i < 4; ++i) {
            ps[blockIdx.x * 16 + wave * 4 + i] = s[i];
            pq[blockIdx.x * 16 + wave * 4 + i] = q[i];
        }
}

// --------------------------------------------- BN finalize over 256 block-partials
__global__ void k_bn_final(const float* __restrict__ ps, const float* __restrict__ pq,
                           const ushort_t* __restrict__ gamma, const ushort_t* __restrict__ beta,
                           float* __restrict__ scale, float* __restrict__ shift)
{
    int t = threadIdx.x;
    int ch = t & 15, seg = t >> 4;
    float s = 0.f, q = 0.f;
    for (int j = 0; j < 64; ++j) {
        int b = seg * 64 + j;
        s += ps[b * 16 + ch]; q += pq[b * 16 + ch];
    }
    s += __shfl_xor(s, 16); q += __shfl_xor(q, 16);
    s += __shfl_xor(s, 32); q += __shfl_xor(q, 32);
    if (t < 16) {
        const float inv = 1.0f / 131072.0f;
        float mean = s * inv;
        float var  = q * inv - mean * mean;
        float sc = b2f(gamma[ch]) * rsqrtf(var + BN_EPS);
        scale[ch] = sc;
        shift[ch] = b2f(beta[ch]) - mean * sc;
    }
}

// --------------------------------------------- BN finalize over 2048 block-partials
__global__ void k_bn_final2(const float* __restrict__ ps, const float* __restrict__ pq,
                            const ushort_t* __restrict__ gamma, const ushort_t* __restrict__ beta,
                            float* __restrict__ scale, float* __restrict__ shift)
{
    int t = threadIdx.x;
    int ch = t & 15, seg = t >> 4;
    float s = 0.f, q = 0.f;
    for (int j = 0; j < 512; ++j) {
        int b = seg * 512 + j;
        s += ps[b * 16 + ch]; q += pq[b * 16 + ch];
    }
    s += __shfl_xor(s, 16); q += __shfl_xor(q, 16);
    s += __shfl_xor(s, 32); q += __shfl_xor(q, 32);
    if (t < 16) {
        const float inv = 1.0f / 131072.0f;
        float mean = s * inv;
        float var  = q * inv - mean * mean;
        float sc = b2f(gamma[ch]) * rsqrtf(var + BN_EPS);
        scale[ch] = sc;
        shift[ch] = b2f(beta[ch]) - mean * sc;
    }
}

// --------------------------------------------- normalize y0 -> xf (bf16)
__global__ __launch_bounds__(256) void k_norm1(const float* __restrict__ y0,
    const float* __restrict__ scale, const float* __restrict__ shift,
    ushort_t* __restrict__ xf)
{
    int idx = blockIdx.x * 1024 + threadIdx.x;
    #pragma unroll
    for (int i = 0; i < 4; ++i) {
        int k = idx + i * 256;
        int ch = (k >> 6) & 15;
        xf[k] = f2b(y0[k] * scale[ch] + shift[ch]);
    }
}

// --------------------------------------------- convert + transpose W [1024,4096]->[4096,1024] bf16
__global__ __launch_bounds__(256) void k_convT(const void* __restrict__ in,
                                               ushort_t* __restrict__ outT,
                                               const int* __restrict__ flags)
{
    __shared__ ushort_t tl[64][65];
    int f32 = flags[0];
    int bx = blockIdx.x * 64, by = blockIdx.y * 64;
    #pragma unroll
    for (int i = 0; i < 16; ++i) {
        int idx = threadIdx.x + i * 256;
        int r = idx >> 6, c = idx & 63;
        tl[r][c] = ld_canon(in, (size_t)(by + r) * 4096 + bx + c, f32);
    }
    __syncthreads();
    #pragma unroll
    for (int i = 0; i < 16; ++i) {
        int idx = threadIdx.x + i * 256;
        int r = idx >> 6, c = idx & 63;
        outT[(size_t)(bx + r) * 1024 + by + c] = tl[c][r];
    }
}

// --------------------------------------------- bf16 GEMM 128x128 tile (register staging)
// A [2048,1024], BT [4096,1024] (=B^T), out [2048,4096] bf16 + bias
__global__ __launch_bounds__(256) void k_gemm(
    const ushort_t* __restrict__ A, const ushort_t* __restrict__ BT,
    const ushort_t* __restrict__ bias, ushort_t* __restrict__ out)
{
    __shared__ __align__(16) ushort_t As[128 * 32];
    __shared__ __align__(16) ushort_t Bs[128 * 32];
    int tid = threadIdx.x;
    int wv = tid >> 6, ln = tid & 63;
    int m0 = blockIdx.y * 128, n0 = blockIdx.x * 128;
    int wm = (wv >> 1) * 64, wn = (wv & 1) * 64;
    int lr = ln & 15, quad = ln >> 4;

    f32x4 acc[4][4];
    #pragma unroll
    for (int i = 0; i < 4; ++i)
        #pragma unroll
        for (int j = 0; j < 4; ++j) acc[i][j] = (f32x4){0.f, 0.f, 0.f, 0.f};

    for (int k0 = 0; k0 < 1024; k0 += 32) {
        __syncthreads();
        #pragma unroll
        for (int i = 0; i < 2; ++i) {
            int ci = i * 256 + tid;
            int m = ci >> 2, kc = ci & 3;
            us8 va = *(const us8*)(A  + (size_t)(m0 + m) * 1024 + k0 + kc * 8);
            us8 vb = *(const us8*)(BT + (size_t)(n0 + m) * 1024 + k0 + kc * 8);
            *(us8*)(&As[ci * 8]) = va;
            *(us8*)(&Bs[ci * 8]) = vb;
        }
        __syncthreads();
        bf16x8 af[4], bfr[4];
        #pragma unroll
        for (int i = 0; i < 4; ++i)
            af[i] = *(const bf16x8*)(&As[(wm + i * 16 + lr) * 32 + quad * 8]);
        #pragma unroll
        for (int j = 0; j < 4; ++j)
            bfr[j] = *(const bf16x8*)(&Bs[(wn + j * 16 + lr) * 32 + quad * 8]);
        #pragma unroll
        for (int i = 0; i < 4; ++i)
            #pragma unroll
            for (int j = 0; j < 4; ++j)
                acc[i][j] = __builtin_amdgcn_mfma_f32_16x16x32_bf16(af[i], bfr[j], acc[i][j], 0, 0, 0);
    }
    #pragma unroll
    for (int j = 0; j < 4; ++j) {
        int col = n0 + wn + j * 16 + lr;
        float bj = b2f(bias[col]);
        #pragma unroll
        for (int i = 0; i < 4; ++i) {
            int rbase = m0 + wm + i * 16 + quad * 4;
            #pragma unroll
            for (int r = 0; r < 4; ++r)
                out[(size_t)(rbase + r) * 4096 + col] = f2b(acc[i][j][r] + bj);
        }
    }
}

// --------------------------------------------- CSR build
__global__ void k_count(const int* __restrict__ cei, int* __restrict__ counts) {
    int idx = blockIdx.x * 256 + threadIdx.x;
    if (idx < E_EDGES) {
        int s = cei[idx], d = cei[E_EDGES + idx];
        if (s != d) atomicAdd(&counts[d], 1);
    } else if (idx < MAXE) {
        atomicAdd(&counts[idx - E_EDGES], 1);
    }
}

__global__ __launch_bounds__(256) void k_scan(const int* __restrict__ counts,
                                              int* __restrict__ offsets, int* __restrict__ cursor)
{
    __shared__ int ts[256];
    int t = threadIdx.x;
    int loc[8]; int tot = 0;
    #pragma unroll
    for (int j = 0; j < 8; ++j) { loc[j] = counts[t * 8 + j]; tot += loc[j]; }
    ts[t] = tot; __syncthreads();
    for (int s = 1; s < 256; s <<= 1) {
        int v = (t >= s) ? ts[t - s] : 0;
        __syncthreads();
        ts[t] += v;
        __syncthreads();
    }
    int run = ts[t] - tot;
    #pragma unroll
    for (int j = 0; j < 8; ++j) {
        offsets[t * 8 + j] = run; cursor[t * 8 + j] = run; run += loc[j];
    }
    if (t == 255) offsets[2048] = run;
}

__global__ void k_scatter(const int* __restrict__ cei, int* __restrict__ cursor,
                          int* __restrict__ esrc)
{
    int idx = blockIdx.x * 256 + threadIdx.x;
    if (idx < E_EDGES) {
        int s = cei[idx], d = cei[E_EDGES + idx];
        if (s != d) { int pos = atomicAdd(&cursor[d], 1); esrc[pos] = s; }
    } else if (idx < MAXE) {
        int i = idx - E_EDGES;
        int pos = atomicAdd(&cursor[i], 1); esrc[pos] = i;
    }
}

// --------------------------------------------- GATv2 edge phase + fused fc2 + BN2 partials
#define CH_E 128
__global__ __launch_bounds__(256) void k_gat(
    const ushort_t* __restrict__ xl, const ushort_t* __restrict__ xr,
    const ushort_t* __restrict__ csm,
    const int* __restrict__ offsets, const int* __restrict__ esrc,
    float* __restrict__ z, float* __restrict__ ps2, float* __restrict__ pq2)
{
    __shared__ float lg[HEADS][CH_E];
    __shared__ int es[CH_E];
    __shared__ float gs[4096];
    __shared__ float sw2[1024];
    __shared__ float sb2[16];
    int d = blockIdx.x;
    int tid = threadIdx.x;
    int h = tid >> 6, l = tid & 63;
    #pragma unroll
    for (int i = 0; i < 4; ++i) sw2[tid + i * 256] = b2f(csm[CW2 + tid + i * 256]);
    if (tid < 16) sb2[tid] = b2f(csm[CB2 + tid]);
    int off = offsets[d], deg = offsets[d + 1] - off;

    float xrv[16], attv[16];
    {
        const ushort_t* xp = xr + ((size_t)d * NF + h * F_DIM + l * 16);
        const ushort_t* ap = csm + (CATT + h * F_DIM + l * 16);
        us8 x0 = *(const us8*)xp, x1 = *(const us8*)(xp + 8);
        us8 a0 = *(const us8*)ap, a1 = *(const us8*)(ap + 8);
        #pragma unroll
        for (int j = 0; j < 8; ++j) {
            xrv[j] = b2f(x0[j]); xrv[8 + j] = b2f(x1[j]);
            attv[j] = b2f(a0[j]); attv[8 + j] = b2f(a1[j]);
        }
    }
    float acc[16];
    #pragma unroll
    for (int j = 0; j < 16; ++j) acc[j] = 0.f;
    float m_run = -3.0e38f, s_run = 0.f;

    for (int c0 = 0; c0 < deg; c0 += CH_E) {
        int cnt = min(CH_E, deg - c0);
        __syncthreads();
        if (tid < cnt) es[tid] = esrc[off + c0 + tid];
        __syncthreads();
        for (int e = 0; e < cnt; ++e) {
            const ushort_t* xp = xl + ((size_t)es[e] * NF + h * F_DIM + l * 16);
            us8 x0 = *(const us8*)xp, x1 = *(const us8*)(xp + 8);
            float t = 0.f;
            #pragma unroll
            for (int j = 0; j < 8; ++j) {
                float v0 = b2f(x0[j]) + xrv[j];     v0 = v0 > 0.f ? v0 : NSLOPE * v0;
                float v1 = b2f(x1[j]) + xrv[8 + j]; v1 = v1 > 0.f ? v1 : NSLOPE * v1;
                t += v0 * attv[j] + v1 * attv[8 + j];
            }
            #pragma unroll
            for (int mm = 1; mm < 64; mm <<= 1) t += __shfl_xor(t, mm);
            if (l == 0) lg[h][e] = t;
        }
        float cmax = -3.0e38f;
        for (int e = l; e < cnt; e += 64) cmax = fmaxf(cmax, lg[h][e]);
        #pragma unroll
        for (int mm = 1; mm < 64; mm <<= 1) cmax = fmaxf(cmax, __shfl_xor(cmax, mm));
        float nm = fmaxf(m_run, cmax);
        float csum = 0.f;
        for (int e = l; e < cnt; e += 64) {
            float w = __expf(lg[h][e] - nm); lg[h][e] = w; csum += w;
        }
        #pragma unroll
        for (int mm = 1; mm < 64; mm <<= 1) csum += __shfl_xor(csum, mm);
        float fac = __expf(m_run - nm);
        s_run = s_run * fac + csum;
        #pragma unroll
        for (int j = 0; j < 16; ++j) acc[j] *= fac;
        for (int e = 0; e < cnt; ++e) {
            float w = lg[h][e];
            const ushort_t* xp = xl + ((size_t)es[e] * NF + h * F_DIM + l * 16);
            us8 x0 = *(const us8*)xp, x1 = *(const us8*)(xp + 8);
            #pragma unroll
            for (int j = 0; j < 8; ++j) {
                acc[j] += w * b2f(x0[j]); acc[8 + j] += w * b2f(x1[j]);
            }
        }
        m_run = nm;
    }
    float inv = (deg > 0) ? 1.0f / s_run : 0.0f;
    #pragma unroll
    for (int j = 0; j < 16; ++j)
        gs[h * 1024 + l * 16 + j] = acc[j] * inv + b2f(csm[CBG + h * F_DIM + l * 16 + j]);
    __syncthreads();

    // fused fc2: z[d][o][p] = b2 + sum_k g[d][k*64+p] * w2[o*64+k]
    float s[4], q[4];
    #pragma unroll
    for (int i = 0; i < 4; ++i) {
        int o = h * 4 + i;
        float zv = sb2[o];
        #pragma unroll
        for (int k = 0; k < 64; ++k) zv += gs[k * 64 + l] * sw2[o * 64 + k];
        z[(size_t)d * 1024 + o * 64 + l] = zv;
        s[i] = zv; q[i] = zv * zv;
    }
    #pragma unroll
    for (int i = 0; i < 4; ++i)
        for (int mm = 1; mm < 64; mm <<= 1) {
            s[i] += __shfl_xor(s[i], mm);
            q[i] += __shfl_xor(q[i], mm);
        }
    if (l == 0)
        #pragma unroll
        for (int i = 0; i < 4; ++i) {
            ps2[d * 16 + h * 4 + i] = s[i];
            pq2[d * 16 + h * 4 + i] = q[i];
        }
}

// --------------------------------------------- BN2 apply + residual -> out (dtype per flag)
__global__ __launch_bounds__(256) void k_out(
    const float* __restrict__ z, const ushort_t* __restrict__ cx,
    const float* __restrict__ scale, const float* __restrict__ shift,
    const int* __restrict__ flags, void* __restrict__ out)
{
    int f32 = flags[0];
    int idx = blockIdx.x * 512 + threadIdx.x;
    #pragma unroll
    for (int i = 0; i < 2; ++i) {
        int k = idx + i * 256;
        int ch = (k >> 6) & 15;
        float val = z[k] * scale[ch] + shift[ch] + b2f(cx[k]);
        if (f32) ((float*)out)[k] = val;
        else     ((ushort_t*)out)[k] = f2b(val);
    }
}

// ================================================================ launch
extern "C" void kernel_launch(void* const* d_in, const int* in_sizes, int n_in,
                              void* d_out, int out_size, void* d_ws, size_t ws_size,
                              hipStream_t stream)
{
    const void* x   = d_in[0];
    const void* ei  = d_in[1];
    const void* w1  = d_in[2];
    const void* b1  = d_in[3];
    const void* g1  = d_in[4];
    const void* be1 = d_in[5];
    const void* wl  = d_in[6];
    const void* bl  = d_in[7];
    const void* wr  = d_in[8];
    const void* br  = d_in[9];
    const void* att = d_in[10];
    const void* bg  = d_in[11];
    const void* w2  = d_in[12];
    const void* b2  = d_in[13];
    const void* g2  = d_in[14];
    const void* be2 = d_in[15];
    (void)in_sizes; (void)n_in; (void)out_size; (void)ws_size;

    char* wsb = (char*)d_ws;
    size_t o = 0;
    auto alloc = [&](size_t bytes) -> void* {
        void* p = wsb + o;
        o = (o + bytes + 255) & ~(size_t)255;
        return p;
    };
    int*      flags = (int*)alloc(256);
    ushort_t* csm   = (ushort_t*)alloc(CSM_N * 2);
    ushort_t* cx    = (ushort_t*)alloc(2097152ull * 2);
    int*      cei   = (int*)alloc(32768 * 4);
    float*    y0    = (float*)alloc(2097152ull * 4);   // reused as z
    float*    z     = y0;
    ushort_t* xf    = (ushort_t*)alloc(2097152ull * 2);
    ushort_t* wT    = (ushort_t*)alloc(4194304ull * 2);
    ushort_t* xlb   = (ushort_t*)alloc(8388608ull * 2);
    ushort_t* xrb   = (ushort_t*)alloc(8388608ull * 2);
    float* p1s = (float*)alloc(256 * 16 * 4);
    float* p1q = (float*)alloc(256 * 16 * 4);
    float* p2s = (float*)alloc(2048 * 16 * 4);
    float* p2q = (float*)alloc(2048 * 16 * 4);
    float* ss  = (float*)alloc(64 * 4);                // scale1,shift1,scale2,shift2
    int* counts = (int*)alloc(2048 * 4);
    int* offs   = (int*)alloc(2049 * 4);
    int* cursor = (int*)alloc(2048 * 4);
    int* esrc   = (int*)alloc(MAXE * 4);

    k_sniff<<<1, 64, 0, stream>>>((const ushort_t*)x, (const int*)ei, flags);
    k_zero<<<8, 256, 0, stream>>>(counts);
    k_convert_all<<<2081, 256, 0, stream>>>(flags, x, ei, w1, b1, g1, be1,
                                            bl, br, att, bg, w2, b2, g2, be2,
                                            cx, cei, csm);
    k_fc1_stats<<<256, 256, 0, stream>>>(cx, csm, y0, p1s, p1q);
    k_bn_final<<<1, 64, 0, stream>>>(p1s, p1q, csm + CG1, csm + CBE1, ss, ss + 16);
    k_norm1<<<2048, 256, 0, stream>>>(y0, ss, ss + 16, xf);
    k_convT<<<dim3(64, 16), 256, 0, stream>>>(wl, wT, flags);
    k_gemm<<<dim3(32, 16), 256, 0, stream>>>(xf, wT, csm + CBL, xlb);
    k_convT<<<dim3(64, 16), 256, 0, stream>>>(wr, wT, flags);
    k_gemm<<<dim3(32, 16), 256, 0, stream>>>(xf, wT, csm + CBR, xrb);
    k_count<<<(MAXE + 255) / 256, 256, 0, stream>>>(cei, counts);
    k_scan<<<1, 256, 0, stream>>>(counts, offs, cursor);
    k_scatter<<<(MAXE + 255) / 256, 256, 0, stream>>>(cei, cursor, esrc);
    k_gat<<<N_NODES, 256, 0, stream>>>(xlb, xrb, csm, offs, esrc, z, p2s, p2q);
    k_bn_final2<<<1, 64, 0, stream>>>(p2s, p2q, csm + CG2, csm + CBE2, ss + 32, ss + 48);
    k_out<<<4096, 256, 0, stream>>>(z, cx, ss + 32, ss + 48, flags, d_out);
}

// Round 3
// 292.810 us; speedup vs baseline: 1.1343x; 1.1343x over previous
//
#include <hip/hip_runtime.h>
#include <stdint.h>

#define N_NODES 2048
#define F_DIM   1024
#define HEADS   4
#define NF      4096
#define ROW     8192          // fused [xl|xr] row width
#define E_EDGES 16384
#define MAXE    (E_EDGES + N_NODES)
#define BN_EPS  1e-5f
#define NSLOPE  0.2f

// canonical small-tensor offsets (elements, all multiples of 8 for 16B alignment)
#define CW1   0
#define CB1   256
#define CG1   272
#define CBE1  288
#define CBL   304            // [bl | br] contiguous 8192
#define CBR   4400
#define CATT  8496
#define CBG   12592
#define CW2   16688
#define CB2   17712
#define CG2   17728
#define CBE2  17744
#define CSM_N 17760

typedef unsigned short ushort_t;
typedef __attribute__((ext_vector_type(8))) short bf16x8;
typedef __attribute__((ext_vector_type(4))) float f32x4;
typedef __attribute__((ext_vector_type(8))) unsigned short us8;

__device__ __forceinline__ float b2f(unsigned short u) {
    union { unsigned int i; float f; } x; x.i = ((unsigned int)u) << 16; return x.f;
}
__device__ __forceinline__ unsigned short f2b(float f) {
    union { float f; unsigned int i; } x; x.f = f;
    unsigned int r = x.i + 0x7fffu + ((x.i >> 16) & 1u);
    return (unsigned short)(r >> 16);
}

// ------------------------------------------------------------- dtype sniff
__global__ void k_sniff(const ushort_t* __restrict__ xu, const int* __restrict__ ei,
                        int* __restrict__ flags)
{
    if (threadIdx.x == 0) {
        int hits = 0;
        for (int i = 0; i < 32; ++i) {
            unsigned e = (xu[2 * i] >> 7) & 0xFF;
            if (e >= 0x90) hits++;
        }
        flags[0] = (hits >= 3) ? 1 : 0;
        int nz = 0;
        for (int i = 0; i < 32; ++i) if (ei[2 * i + 1] != 0) nz++;
        flags[1] = (nz == 0) ? 1 : 0;
    }
}

// ------------------------------------------------------------- canonicalize inputs
__device__ __forceinline__ ushort_t ld_canon(const void* src, size_t i, int f32) {
    return f32 ? f2b(((const float*)src)[i]) : ((const ushort_t*)src)[i];
}

__global__ __launch_bounds__(256) void k_convert_all(
    const int* __restrict__ flags,
    const void* x, const void* ei,
    const void* w1, const void* b1, const void* g1, const void* be1,
    const void* bl, const void* br, const void* att, const void* bg,
    const void* w2, const void* b2, const void* g2, const void* be2,
    ushort_t* __restrict__ cx, int* __restrict__ cei, ushort_t* __restrict__ csm)
{
    int f32 = flags[0], i64 = flags[1];
    int b = blockIdx.x, t = threadIdx.x;
    if (b < 2048) {
        size_t base = (size_t)b * 1024;
        #pragma unroll
        for (int i = 0; i < 4; ++i) {
            size_t idx = base + t + i * 256;
            cx[idx] = ld_canon(x, idx, f32);
        }
    } else if (b == 2048) {
        for (int i = t; i < 256; i += 256)  csm[CW1 + i]  = ld_canon(w1, i, f32);
        for (int i = t; i < 16; i += 256)   csm[CB1 + i]  = ld_canon(b1, i, f32);
        for (int i = t; i < 16; i += 256)   csm[CG1 + i]  = ld_canon(g1, i, f32);
        for (int i = t; i < 16; i += 256)   csm[CBE1 + i] = ld_canon(be1, i, f32);
        for (int i = t; i < 4096; i += 256) csm[CBL + i]  = ld_canon(bl, i, f32);
        for (int i = t; i < 4096; i += 256) csm[CBR + i]  = ld_canon(br, i, f32);
        for (int i = t; i < 4096; i += 256) csm[CATT + i] = ld_canon(att, i, f32);
        for (int i = t; i < 4096; i += 256) csm[CBG + i]  = ld_canon(bg, i, f32);
        for (int i = t; i < 1024; i += 256) csm[CW2 + i]  = ld_canon(w2, i, f32);
        for (int i = t; i < 16; i += 256)   csm[CB2 + i]  = ld_canon(b2, i, f32);
        for (int i = t; i < 16; i += 256)   csm[CG2 + i]  = ld_canon(g2, i, f32);
        for (int i = t; i < 16; i += 256)   csm[CBE2 + i] = ld_canon(be2, i, f32);
    } else {
        const int* s = (const int*)ei;
        int base = (b - 2049) * 1024;
        #pragma unroll
        for (int j = 0; j < 4; ++j) {
            int idx = base + t + j * 256;
            cei[idx] = i64 ? s[2 * idx] : s[idx];
        }
    }
}

// ------------------------------------------------- fc1 (conv1x1 16->16) + BN1 partials
__global__ __launch_bounds__(256) void k_fc1_stats(
    const ushort_t* __restrict__ cx, const ushort_t* __restrict__ csm,
    float* __restrict__ y0, float* __restrict__ ps, float* __restrict__ pq)
{
    __shared__ float xs[1024];
    __shared__ float sw[256];
    __shared__ float sb[16];
    int tid = threadIdx.x;
    sw[tid] = b2f(csm[CW1 + tid]);
    if (tid < 16) sb[tid] = b2f(csm[CB1 + tid]);
    int wave = tid >> 6, lane = tid & 63;
    float s[4] = {0,0,0,0}, q[4] = {0,0,0,0};
    for (int nn = 0; nn < 8; ++nn) {
        int n = blockIdx.x * 8 + nn;
        __syncthreads();
        #pragma unroll
        for (int i = 0; i < 4; ++i) {
            int idx = tid + i * 256;
            xs[idx] = b2f(cx[(size_t)n * 1024 + idx]);
        }
        __syncthreads();
        #pragma unroll
        for (int i = 0; i < 4; ++i) {
            int o = wave * 4 + i;
            float acc = sb[o];
            #pragma unroll
            for (int c = 0; c < 16; ++c) acc += xs[c * 64 + lane] * sw[o * 16 + c];
            y0[(size_t)n * 1024 + o * 64 + lane] = acc;
            s[i] += acc; q[i] += acc * acc;
        }
    }
    #pragma unroll
    for (int i = 0; i < 4; ++i)
        for (int mm = 1; mm < 64; mm <<= 1) {
            s[i] += __shfl_xor(s[i], mm);
            q[i] += __shfl_xor(q[i], mm);
        }
    if (lane == 0)
        #pragma unroll
        for (int i = 0; i < 4; ++i) {
            ps[blockIdx.x * 16 + wave * 4 + i] = s[i];
            pq[blockIdx.x * 16 + wave * 4 + i] = q[i];
        }
}

// --------------------------------------------- BN finalize over 256 block-partials
__global__ void k_bn_final(const float* __restrict__ ps, const float* __restrict__ pq,
                           const ushort_t* __restrict__ gamma, const ushort_t* __restrict__ beta,
                           float* __restrict__ scale, float* __restrict__ shift)
{
    int t = threadIdx.x;
    int ch = t & 15, seg = t >> 4;
    float s = 0.f, q = 0.f;
    for (int j = 0; j < 64; ++j) {
        int b = seg * 64 + j;
        s += ps[b * 16 + ch]; q += pq[b * 16 + ch];
    }
    s += __shfl_xor(s, 16); q += __shfl_xor(q, 16);
    s += __shfl_xor(s, 32); q += __shfl_xor(q, 32);
    if (t < 16) {
        const float inv = 1.0f / 131072.0f;
        float mean = s * inv;
        float var  = q * inv - mean * mean;
        float sc = b2f(gamma[ch]) * rsqrtf(var + BN_EPS);
        scale[ch] = sc;
        shift[ch] = b2f(beta[ch]) - mean * sc;
    }
}

// --------------------------------------------- BN finalize over 2048 block-partials
__global__ void k_bn_final2(const float* __restrict__ ps, const float* __restrict__ pq,
                            const ushort_t* __restrict__ gamma, const ushort_t* __restrict__ beta,
                            float* __restrict__ scale, float* __restrict__ shift)
{
    int t = threadIdx.x;
    int ch = t & 15, seg = t >> 4;
    float s = 0.f, q = 0.f;
    for (int j = 0; j < 512; ++j) {
        int b = seg * 512 + j;
        s += ps[b * 16 + ch]; q += pq[b * 16 + ch];
    }
    s += __shfl_xor(s, 16); q += __shfl_xor(q, 16);
    s += __shfl_xor(s, 32); q += __shfl_xor(q, 32);
    if (t < 16) {
        const float inv = 1.0f / 131072.0f;
        float mean = s * inv;
        float var  = q * inv - mean * mean;
        float sc = b2f(gamma[ch]) * rsqrtf(var + BN_EPS);
        scale[ch] = sc;
        shift[ch] = b2f(beta[ch]) - mean * sc;
    }
}

// --------------------------------------------- normalize y0 -> xf (bf16)
__global__ __launch_bounds__(256) void k_norm1(const float* __restrict__ y0,
    const float* __restrict__ scale, const float* __restrict__ shift,
    ushort_t* __restrict__ xf)
{
    int idx = blockIdx.x * 1024 + threadIdx.x;
    #pragma unroll
    for (int i = 0; i < 4; ++i) {
        int k = idx + i * 256;
        int ch = (k >> 6) & 15;
        xf[k] = f2b(y0[k] * scale[ch] + shift[ch]);
    }
}

// --------------------------------------------- convert + transpose W [1024,4096]->[4096,1024] bf16
__global__ __launch_bounds__(256) void k_convT(const void* __restrict__ in,
                                               ushort_t* __restrict__ outT,
                                               const int* __restrict__ flags)
{
    __shared__ ushort_t tl[64][65];
    int f32 = flags[0];
    int bx = blockIdx.x * 64, by = blockIdx.y * 64;
    #pragma unroll
    for (int i = 0; i < 16; ++i) {
        int idx = threadIdx.x + i * 256;
        int r = idx >> 6, c = idx & 63;
        tl[r][c] = ld_canon(in, (size_t)(by + r) * 4096 + bx + c, f32);
    }
    __syncthreads();
    #pragma unroll
    for (int i = 0; i < 16; ++i) {
        int idx = threadIdx.x + i * 256;
        int r = idx >> 6, c = idx & 63;
        outT[(size_t)(bx + r) * 1024 + by + c] = tl[c][r];
    }
}

// --------------------------------------------- fused bf16 GEMM (m97 structure)
// A [2048,1024], BT [8192,1024] (=[wl|wr]^T), out [2048,8192] bf16 + bias
__global__ __launch_bounds__(256) void k_gemm(
    const ushort_t* __restrict__ A, const ushort_t* __restrict__ BT,
    const ushort_t* __restrict__ bias, ushort_t* __restrict__ out)
{
    __shared__ __align__(16) ushort_t As[128 * 32];
    __shared__ __align__(16) ushort_t Bs[128 * 32];
    int tid = threadIdx.x;
    int wv = tid >> 6, ln = tid & 63;
    int m0 = blockIdx.y * 128, n0 = blockIdx.x * 128;
    int wm = (wv >> 1) * 64, wn = (wv & 1) * 64;
    int lr = ln & 15, quad = ln >> 4;

    f32x4 acc[4][4];
    #pragma unroll
    for (int i = 0; i < 4; ++i)
        #pragma unroll
        for (int j = 0; j < 4; ++j) acc[i][j] = (f32x4){0.f, 0.f, 0.f, 0.f};

    for (int k0 = 0; k0 < 1024; k0 += 32) {
        #pragma unroll
        for (int i = 0; i < 2; ++i) {
            int cbase = i * 256 + wv * 64;     // wave-uniform LDS chunk base
            int ci = cbase + ln;
            int m = ci >> 2, kc = ci & 3;
            const ushort_t* ga = A + (size_t)(m0 + m) * 1024 + k0 + kc * 8;
            __builtin_amdgcn_global_load_lds(
                (const __attribute__((address_space(1))) void*)ga,
                (__attribute__((address_space(3))) void*)(&As[cbase * 8]), 16, 0, 0);
            const ushort_t* gb = BT + (size_t)(n0 + m) * 1024 + k0 + kc * 8;
            __builtin_amdgcn_global_load_lds(
                (const __attribute__((address_space(1))) void*)gb,
                (__attribute__((address_space(3))) void*)(&Bs[cbase * 8]), 16, 0, 0);
        }
        __syncthreads();
        bf16x8 af[4], bfr[4];
        #pragma unroll
        for (int i = 0; i < 4; ++i)
            af[i] = *(const bf16x8*)(&As[(wm + i * 16 + lr) * 32 + quad * 8]);
        #pragma unroll
        for (int j = 0; j < 4; ++j)
            bfr[j] = *(const bf16x8*)(&Bs[(wn + j * 16 + lr) * 32 + quad * 8]);
        #pragma unroll
        for (int i = 0; i < 4; ++i)
            #pragma unroll
            for (int j = 0; j < 4; ++j)
                acc[i][j] = __builtin_amdgcn_mfma_f32_16x16x32_bf16(af[i], bfr[j], acc[i][j], 0, 0, 0);
        __syncthreads();
    }
    #pragma unroll
    for (int j = 0; j < 4; ++j) {
        int col = n0 + wn + j * 16 + lr;
        float bj = b2f(bias[col]);
        #pragma unroll
        for (int i = 0; i < 4; ++i) {
            int rbase = m0 + wm + i * 16 + quad * 4;
            #pragma unroll
            for (int r = 0; r < 4; ++r)
                out[(size_t)(rbase + r) * ROW + col] = f2b(acc[i][j][r] + bj);
        }
    }
}

// --------------------------------------------- CSR build
__global__ void k_count(const int* __restrict__ cei, int* __restrict__ counts) {
    int idx = blockIdx.x * 256 + threadIdx.x;
    if (idx < E_EDGES) {
        int s = cei[idx], d = cei[E_EDGES + idx];
        if (s != d) atomicAdd(&counts[d], 1);
    } else if (idx < MAXE) {
        atomicAdd(&counts[idx - E_EDGES], 1);
    }
}

__global__ __launch_bounds__(256) void k_scan(const int* __restrict__ counts,
                                              int* __restrict__ offsets, int* __restrict__ cursor)
{
    __shared__ int ts[256];
    int t = threadIdx.x;
    int loc[8]; int tot = 0;
    #pragma unroll
    for (int j = 0; j < 8; ++j) { loc[j] = counts[t * 8 + j]; tot += loc[j]; }
    ts[t] = tot; __syncthreads();
    for (int s = 1; s < 256; s <<= 1) {
        int v = (t >= s) ? ts[t - s] : 0;
        __syncthreads();
        ts[t] += v;
        __syncthreads();
    }
    int run = ts[t] - tot;
    #pragma unroll
    for (int j = 0; j < 8; ++j) {
        offsets[t * 8 + j] = run; cursor[t * 8 + j] = run; run += loc[j];
    }
    if (t == 255) offsets[2048] = run;
}

__global__ void k_scatter(const int* __restrict__ cei, int* __restrict__ cursor,
                          int* __restrict__ esrc)
{
    int idx = blockIdx.x * 256 + threadIdx.x;
    if (idx < E_EDGES) {
        int s = cei[idx], d = cei[E_EDGES + idx];
        if (s != d) { int pos = atomicAdd(&cursor[d], 1); esrc[pos] = s; }
    } else if (idx < MAXE) {
        int i = idx - E_EDGES;
        int pos = atomicAdd(&cursor[i], 1); esrc[pos] = i;
    }
}

// --------------------------------------------- GATv2: single-pass online softmax
// + fused fc2 + BN2 partials. One block per dst, wave = head, lane = 16 feats.
#define CH_E 64
__global__ __launch_bounds__(256) void k_gat(
    const ushort_t* __restrict__ xlr,           // [2048, 8192] = [xl|xr]
    const ushort_t* __restrict__ csm,
    const int* __restrict__ offsets, const int* __restrict__ esrc,
    float* __restrict__ z, float* __restrict__ ps2, float* __restrict__ pq2)
{
    __shared__ int es[CH_E];
    __shared__ ushort_t gsb[4096];              // g row, bf16
    __shared__ float sw2[1024];
    __shared__ float sb2[16];
    int d = blockIdx.x;
    int tid = threadIdx.x;
    int h = tid >> 6, l = tid & 63;
    #pragma unroll
    for (int i = 0; i < 4; ++i) sw2[tid + i * 256] = b2f(csm[CW2 + tid + i * 256]);
    if (tid < 16) sb2[tid] = b2f(csm[CB2 + tid]);
    int off = offsets[d], deg = offsets[d + 1] - off;

    float xrv[16], attv[16];
    {
        const ushort_t* xp = xlr + ((size_t)d * ROW + NF + h * F_DIM + l * 16);
        const ushort_t* ap = csm + (CATT + h * F_DIM + l * 16);
        us8 x0 = *(const us8*)xp, x1 = *(const us8*)(xp + 8);
        us8 a0 = *(const us8*)ap, a1 = *(const us8*)(ap + 8);
        #pragma unroll
        for (int j = 0; j < 8; ++j) {
            xrv[j] = b2f(x0[j]); xrv[8 + j] = b2f(x1[j]);
            attv[j] = b2f(a0[j]); attv[8 + j] = b2f(a1[j]);
        }
    }
    float acc[16];
    #pragma unroll
    for (int j = 0; j < 16; ++j) acc[j] = 0.f;
    float m_run = -3.0e38f, s_run = 0.f;

    for (int c0 = 0; c0 < deg; c0 += CH_E) {
        int cnt = min(CH_E, deg - c0);
        __syncthreads();
        if (tid < cnt) es[tid] = esrc[off + c0 + tid];
        __syncthreads();
        int e = 0;
        for (; e + 1 < cnt; e += 2) {               // 2-edge pipeline
            const ushort_t* p0 = xlr + ((size_t)es[e]     * ROW + h * F_DIM + l * 16);
            const ushort_t* p1 = xlr + ((size_t)es[e + 1] * ROW + h * F_DIM + l * 16);
            us8 a0 = *(const us8*)p0, a1 = *(const us8*)(p0 + 8);
            us8 b0 = *(const us8*)p1, b1 = *(const us8*)(p1 + 8);
            float t0 = 0.f, t1 = 0.f;
            #pragma unroll
            for (int j = 0; j < 8; ++j) {
                float u;
                u = b2f(a0[j]) + xrv[j];     u = u > 0.f ? u : NSLOPE * u; t0 += u * attv[j];
                u = b2f(a1[j]) + xrv[8 + j]; u = u > 0.f ? u : NSLOPE * u; t0 += u * attv[8 + j];
                u = b2f(b0[j]) + xrv[j];     u = u > 0.f ? u : NSLOPE * u; t1 += u * attv[j];
                u = b2f(b1[j]) + xrv[8 + j]; u = u > 0.f ? u : NSLOPE * u; t1 += u * attv[8 + j];
            }
            #pragma unroll
            for (int mm = 1; mm < 64; mm <<= 1) {
                t0 += __shfl_xor(t0, mm);
                t1 += __shfl_xor(t1, mm);
            }
            float nm = fmaxf(m_run, fmaxf(t0, t1));
            float fac = __expf(m_run - nm);
            float w0 = __expf(t0 - nm), w1 = __expf(t1 - nm);
            s_run = s_run * fac + w0 + w1;
            #pragma unroll
            for (int j = 0; j < 8; ++j) {
                acc[j]     = acc[j]     * fac + w0 * b2f(a0[j]) + w1 * b2f(b0[j]);
                acc[8 + j] = acc[8 + j] * fac + w0 * b2f(a1[j]) + w1 * b2f(b1[j]);
            }
            m_run = nm;
        }
        if (e < cnt) {                              // tail edge
            const ushort_t* p0 = xlr + ((size_t)es[e] * ROW + h * F_DIM + l * 16);
            us8 a0 = *(const us8*)p0, a1 = *(const us8*)(p0 + 8);
            float t0 = 0.f;
            #pragma unroll
            for (int j = 0; j < 8; ++j) {
                float u;
                u = b2f(a0[j]) + xrv[j];     u = u > 0.f ? u : NSLOPE * u; t0 += u * attv[j];
                u = b2f(a1[j]) + xrv[8 + j]; u = u > 0.f ? u : NSLOPE * u; t0 += u * attv[8 + j];
            }
            #pragma unroll
            for (int mm = 1; mm < 64; mm <<= 1) t0 += __shfl_xor(t0, mm);
            float nm = fmaxf(m_run, t0);
            float fac = __expf(m_run - nm);
            float w0 = __expf(t0 - nm);
            s_run = s_run * fac + w0;
            #pragma unroll
            for (int j = 0; j < 8; ++j) {
                acc[j]     = acc[j]     * fac + w0 * b2f(a0[j]);
                acc[8 + j] = acc[8 + j] * fac + w0 * b2f(a1[j]);
            }
            m_run = nm;
        }
    }
    float inv = 1.0f / s_run;
    #pragma unroll
    for (int j = 0; j < 16; ++j)
        gsb[h * 1024 + l * 16 + j] = f2b(acc[j] * inv + b2f(csm[CBG + h * F_DIM + l * 16 + j]));
    __syncthreads();

    // fused fc2: z[d][o*64+p] = b2 + sum_k g[k*64+p] * w2[o*64+k]
    float s[4], q[4];
    #pragma unroll
    for (int i = 0; i < 4; ++i) {
        int o = h * 4 + i;
        float zv = sb2[o];
        #pragma unroll
        for (int k = 0; k < 64; ++k) zv += b2f(gsb[k * 64 + l]) * sw2[o * 64 + k];
        z[(size_t)d * 1024 + o * 64 + l] = zv;
        s[i] = zv; q[i] = zv * zv;
    }
    #pragma unroll
    for (int i = 0; i < 4; ++i)
        for (int mm = 1; mm < 64; mm <<= 1) {
            s[i] += __shfl_xor(s[i], mm);
            q[i] += __shfl_xor(q[i], mm);
        }
    if (l == 0)
        #pragma unroll
        for (int i = 0; i < 4; ++i) {
            ps2[d * 16 + h * 4 + i] = s[i];
            pq2[d * 16 + h * 4 + i] = q[i];
        }
}

// --------------------------------------------- BN2 apply + residual -> out
__global__ __launch_bounds__(256) void k_out(
    const float* __restrict__ z, const ushort_t* __restrict__ cx,
    const float* __restrict__ scale, const float* __restrict__ shift,
    const int* __restrict__ flags, void* __restrict__ out)
{
    int f32 = flags[0];
    int idx = blockIdx.x * 512 + threadIdx.x;
    #pragma unroll
    for (int i = 0; i < 2; ++i) {
        int k = idx + i * 256;
        int ch = (k >> 6) & 15;
        float val = z[k] * scale[ch] + shift[ch] + b2f(cx[k]);
        if (f32) ((float*)out)[k] = val;
        else     ((ushort_t*)out)[k] = f2b(val);
    }
}

// ================================================================ launch
extern "C" void kernel_launch(void* const* d_in, const int* in_sizes, int n_in,
                              void* d_out, int out_size, void* d_ws, size_t ws_size,
                              hipStream_t stream)
{
    const void* x   = d_in[0];
    const void* ei  = d_in[1];
    const void* w1  = d_in[2];
    const void* b1  = d_in[3];
    const void* g1  = d_in[4];
    const void* be1 = d_in[5];
    const void* wl  = d_in[6];
    const void* bl  = d_in[7];
    const void* wr  = d_in[8];
    const void* br  = d_in[9];
    const void* att = d_in[10];
    const void* bg  = d_in[11];
    const void* w2  = d_in[12];
    const void* b2  = d_in[13];
    const void* g2  = d_in[14];
    const void* be2 = d_in[15];
    (void)in_sizes; (void)n_in; (void)out_size; (void)ws_size;

    char* wsb = (char*)d_ws;
    size_t o = 0;
    auto alloc = [&](size_t bytes) -> void* {
        void* p = wsb + o;
        o = (o + bytes + 255) & ~(size_t)255;
        return p;
    };
    int*      flags = (int*)alloc(256);
    ushort_t* csm   = (ushort_t*)alloc(CSM_N * 2);
    ushort_t* cx    = (ushort_t*)alloc(2097152ull * 2);
    int*      cei   = (int*)alloc(32768 * 4);
    float*    y0    = (float*)alloc(2097152ull * 4);   // reused as z
    float*    z     = y0;
    ushort_t* xf    = (ushort_t*)alloc(2097152ull * 2);
    ushort_t* wT    = (ushort_t*)alloc(8388608ull * 2);  // [8192,1024]
    ushort_t* xlr   = (ushort_t*)alloc(16777216ull * 2); // [2048,8192]
    float* p1s = (float*)alloc(256 * 16 * 4);
    float* p1q = (float*)alloc(256 * 16 * 4);
    float* p2s = (float*)alloc(2048 * 16 * 4);
    float* p2q = (float*)alloc(2048 * 16 * 4);
    float* ss  = (float*)alloc(64 * 4);                // scale1,shift1,scale2,shift2
    int* counts = (int*)alloc(2048 * 4);
    int* offs   = (int*)alloc(2049 * 4);
    int* cursor = (int*)alloc(2048 * 4);
    int* esrc   = (int*)alloc(MAXE * 4);

    k_sniff<<<1, 64, 0, stream>>>((const ushort_t*)x, (const int*)ei, flags);
    hipMemsetAsync(counts, 0, 2048 * 4, stream);
    k_convert_all<<<2081, 256, 0, stream>>>(flags, x, ei, w1, b1, g1, be1,
                                            bl, br, att, bg, w2, b2, g2, be2,
                                            cx, cei, csm);
    k_fc1_stats<<<256, 256, 0, stream>>>(cx, csm, y0, p1s, p1q);
    k_bn_final<<<1, 64, 0, stream>>>(p1s, p1q, csm + CG1, csm + CBE1, ss, ss + 16);
    k_norm1<<<2048, 256, 0, stream>>>(y0, ss, ss + 16, xf);
    k_convT<<<dim3(64, 16), 256, 0, stream>>>(wl, wT, flags);
    k_convT<<<dim3(64, 16), 256, 0, stream>>>(wr, wT + 4194304ull, flags);
    k_gemm<<<dim3(64, 16), 256, 0, stream>>>(xf, wT, csm + CBL, xlr);
    k_count<<<(MAXE + 255) / 256, 256, 0, stream>>>(cei, counts);
    k_scan<<<1, 256, 0, stream>>>(counts, offs, cursor);
    k_scatter<<<(MAXE + 255) / 256, 256, 0, stream>>>(cei, cursor, esrc);
    k_gat<<<N_NODES, 256, 0, stream>>>(xlr, csm, offs, esrc, z, p2s, p2q);
    k_bn_final2<<<1, 64, 0, stream>>>(p2s, p2q, csm + CG2, csm + CBE2, ss + 32, ss + 48);
    k_out<<<4096, 256, 0, stream>>>(z, cx, ss + 32, ss + 48, flags, d_out);
}